// Round 9
// baseline (277.194 us; speedup 1.0000x reference)
//
#include <hip/hip_runtime.h>
#include <cstdint>
#include <cstddef>

typedef __attribute__((ext_vector_type(8))) short short8;
typedef __attribute__((ext_vector_type(8))) unsigned short ushort8;
typedef __attribute__((ext_vector_type(4))) float f32x4;
typedef __attribute__((ext_vector_type(8))) _Float16 half8;
typedef __attribute__((ext_vector_type(2))) __fp16 fp16x2;

#define DEV static __device__ __forceinline__

DEV unsigned short f2bf(float x) {
  union { float f; unsigned u; } v; v.f = x;
  unsigned r = v.u + 0x7fffu + ((v.u >> 16) & 1u);
  return (unsigned short)(r >> 16);
}
DEV float bf2f(unsigned short u) {
  union { unsigned u; float f; } v; v.u = ((unsigned)u) << 16;
  return v.f;
}
DEV unsigned pack2bf(float lo, float hi) {
  union { float f; unsigned u; } a, b; a.f = lo; b.f = hi;
  return __builtin_amdgcn_perm(b.u + 0x8000u, a.u + 0x8000u, 0x07060302u);
}
DEV f32x4 mfma16(short8 a, short8 b, f32x4 c) {
  return __builtin_amdgcn_mfma_f32_16x16x32_bf16(a, b, c, 0, 0, 0);
}
DEV f32x4 mfma16h(half8 a, half8 b, f32x4 c) {
  return __builtin_amdgcn_mfma_f32_16x16x32_f16(a, b, c, 0, 0, 0);
}

// async global->LDS, 16B per lane; LDS dst = wave-uniform base + lane*16
typedef __attribute__((address_space(1))) unsigned int g_u32;
typedef __attribute__((address_space(3))) unsigned int l_u32;
DEV void glds16(const unsigned short* g, unsigned short* l) {
  __builtin_amdgcn_global_load_lds((g_u32*)g, (l_u32*)l, 16, 0, 0);
}

constexpr int Bc = 4, Nc = 2048, Dc = 1024, Hc = 16, DKc = 16, DVc = 64, DIc = 1280;
constexpr int Mc = Bc * Nc;  // 8192

// ---------------- elementwise fp32 -> bf16 ----------------
__global__ __launch_bounds__(256) void convert_x(const float* __restrict__ X,
                                                 unsigned short* __restrict__ Xb, int total8) {
  int i = blockIdx.x * 256 + threadIdx.x;
  if (i >= total8) return;
  const float4* p = (const float4*)(X + (size_t)i * 8);
  float4 a = p[0], b = p[1];
  ushort8 o;
  o[0] = f2bf(a.x); o[1] = f2bf(a.y); o[2] = f2bf(a.z); o[3] = f2bf(a.w);
  o[4] = f2bf(b.x); o[5] = f2bf(b.y); o[6] = f2bf(b.z); o[7] = f2bf(b.w);
  *(ushort8*)(Xb + (size_t)i * 8) = o;
}

// ---------------- W[K][N] fp32 -> WT[N][K] bf16 ----------------
__global__ __launch_bounds__(256) void transpose_convert(const float* __restrict__ W,
                                                         unsigned short* __restrict__ WT,
                                                         int K, int N) {
  __shared__ unsigned short t[64][72];
  int k0 = blockIdx.x * 64, n0 = blockIdx.y * 64;
  int tid = threadIdx.x;
#pragma unroll
  for (int it = 0; it < 16; ++it) {
    int f = it * 256 + tid;
    int r = f >> 6, c = f & 63;
    t[c][r] = f2bf(W[(size_t)(k0 + r) * N + n0 + c]);
  }
  __syncthreads();
#pragma unroll
  for (int it = 0; it < 16; ++it) {
    int f = it * 256 + tid;
    int r = f >> 6, c = f & 63;
    WT[(size_t)(n0 + r) * K + k0 + c] = t[r][c];
  }
}

// ---------------- fused projection GEMM: C = Xbf * [WqgT | WkvT]^T ----------------
__global__ __launch_bounds__(256) void gemm_proj(const unsigned short* __restrict__ A,
                                                 const unsigned short* __restrict__ BT,
                                                 unsigned short* __restrict__ QG,
                                                 unsigned short* __restrict__ KV,
                                                 int Kq) {
  __shared__ unsigned short As[128 * 64];
  __shared__ unsigned short Bs[128 * 64];
  int row0 = blockIdx.x * 128, col0 = blockIdx.y * 128;
  int tid = threadIdx.x, lane = tid & 63, wave = tid >> 6;
  int wm = wave >> 1, wn = wave & 1;
  int ql = lane >> 4, l16 = lane & 15;
  int r8 = lane >> 3, cbl = (lane & 7) ^ r8;

  unsigned short* dst = (col0 >= DIc) ? KV : QG;
  int c0l = (col0 >= DIc) ? col0 - DIc : col0;

  const unsigned short* gA = A + (size_t)(row0 + wave * 32 + r8) * Kq + cbl * 8;
  const unsigned short* gB = BT + (size_t)(col0 + wave * 32 + r8) * Kq + cbl * 8;

  f32x4 acc[4][4];
#pragma unroll
  for (int i = 0; i < 4; i++)
#pragma unroll
    for (int j = 0; j < 4; j++) acc[i][j] = (f32x4){0.f, 0.f, 0.f, 0.f};

  for (int k0 = 0; k0 < Kq; k0 += 64) {
    __syncthreads();
#pragma unroll
    for (int i = 0; i < 4; ++i) {
      glds16(gA + (size_t)(i * 8) * Kq + k0, &As[(wave * 32 + i * 8) * 64]);
      glds16(gB + (size_t)(i * 8) * Kq + k0, &Bs[(wave * 32 + i * 8) * 64]);
    }
    __syncthreads();
#pragma unroll
    for (int kk = 0; kk < 64; kk += 32) {
      short8 af[4], bfr[4];
#pragma unroll
      for (int t = 0; t < 4; t++) {
        int row = wm * 64 + t * 16 + l16;
        int cb = (kk >> 3) + ql;
        af[t] = *(const short8*)&As[row * 64 + ((cb ^ (row & 7)) << 3)];
      }
#pragma unroll
      for (int t = 0; t < 4; t++) {
        int row = wn * 64 + t * 16 + l16;
        int cb = (kk >> 3) + ql;
        bfr[t] = *(const short8*)&Bs[row * 64 + ((cb ^ (row & 7)) << 3)];
      }
#pragma unroll
      for (int i = 0; i < 4; i++)
#pragma unroll
        for (int j = 0; j < 4; j++) acc[i][j] = mfma16(af[i], bfr[j], acc[i][j]);
    }
  }
#pragma unroll
  for (int i = 0; i < 4; i++)
#pragma unroll
    for (int j = 0; j < 4; j++)
#pragma unroll
      for (int r = 0; r < 4; r++) {
        int rr = row0 + wm * 64 + i * 16 + ql * 4 + r;
        int cc = c0l + wn * 64 + j * 16 + l16;
        dst[(size_t)rr * DIc + cc] = f2bf(acc[i][j][r]);
      }
}

// ---------------- C[M][N] = A[M][K] * BT[N][K]^T (final GEMM, fp32 out) ----------------
__global__ __launch_bounds__(256) void gemm_glds(const unsigned short* __restrict__ A,
                                                 const unsigned short* __restrict__ BT,
                                                 float* __restrict__ Cout,
                                                 int Mq, int Nq, int Kq) {
  __shared__ unsigned short As[128 * 64];
  __shared__ unsigned short Bs[128 * 64];
  int row0 = blockIdx.x * 128, col0 = blockIdx.y * 128;
  int tid = threadIdx.x, lane = tid & 63, wave = tid >> 6;
  int wm = wave >> 1, wn = wave & 1;
  int ql = lane >> 4, l16 = lane & 15;
  int r8 = lane >> 3, cbl = (lane & 7) ^ r8;

  const unsigned short* gA = A + (size_t)(row0 + wave * 32 + r8) * Kq + cbl * 8;
  const unsigned short* gB = BT + (size_t)(col0 + wave * 32 + r8) * Kq + cbl * 8;

  f32x4 acc[4][4];
#pragma unroll
  for (int i = 0; i < 4; i++)
#pragma unroll
    for (int j = 0; j < 4; j++) acc[i][j] = (f32x4){0.f, 0.f, 0.f, 0.f};

  for (int k0 = 0; k0 < Kq; k0 += 64) {
    __syncthreads();
#pragma unroll
    for (int i = 0; i < 4; ++i) {
      glds16(gA + (size_t)(i * 8) * Kq + k0, &As[(wave * 32 + i * 8) * 64]);
      glds16(gB + (size_t)(i * 8) * Kq + k0, &Bs[(wave * 32 + i * 8) * 64]);
    }
    __syncthreads();
#pragma unroll
    for (int kk = 0; kk < 64; kk += 32) {
      short8 af[4], bfr[4];
#pragma unroll
      for (int t = 0; t < 4; t++) {
        int row = wm * 64 + t * 16 + l16;
        int cb = (kk >> 3) + ql;
        af[t] = *(const short8*)&As[row * 64 + ((cb ^ (row & 7)) << 3)];
      }
#pragma unroll
      for (int t = 0; t < 4; t++) {
        int row = wn * 64 + t * 16 + l16;
        int cb = (kk >> 3) + ql;
        bfr[t] = *(const short8*)&Bs[row * 64 + ((cb ^ (row & 7)) << 3)];
      }
#pragma unroll
      for (int i = 0; i < 4; i++)
#pragma unroll
        for (int j = 0; j < 4; j++) acc[i][j] = mfma16(af[i], bfr[j], acc[i][j]);
    }
  }
#pragma unroll
  for (int i = 0; i < 4; i++)
#pragma unroll
    for (int j = 0; j < 4; j++)
#pragma unroll
      for (int r = 0; r < 4; r++) {
        int rr = row0 + wm * 64 + i * 16 + ql * 4 + r;
        int cc = col0 + wn * 64 + j * 16 + l16;
        Cout[(size_t)rr * Nq + cc] = acc[i][j][r];
      }
}

// ---------------- per-head normalize -> fp16 (Q/K zero-padded to 32 dims) ----------------
__global__ __launch_bounds__(256) void norm_kernel(const unsigned short* __restrict__ QG,
                                                   const unsigned short* __restrict__ KV,
                                                   unsigned short* __restrict__ Qn,   // fp16 [bh][n][32]
                                                   unsigned short* __restrict__ Kn,   // fp16 [bh][n][32]
                                                   unsigned short* __restrict__ Vtg)  // fp16 [bh][d][n]
{
  int g = blockIdx.x * 256 + threadIdx.x;
  int n = g & (Nc - 1), bh = g >> 11;
  int h = bh & 15, b = bh >> 4;
  size_t src = ((size_t)(b * Nc + n)) * DIc + h * 80;
  const ushort8 zeros = {0, 0, 0, 0, 0, 0, 0, 0};

  {
    ushort8 u0 = *(const ushort8*)&QG[src];
    ushort8 u1 = *(const ushort8*)&QG[src + 8];
    float q[16], ss = 0.f;
#pragma unroll
    for (int i = 0; i < 8; i++) { q[i] = bf2f(u0[i]); q[8 + i] = bf2f(u1[i]); }
#pragma unroll
    for (int i = 0; i < 16; i++) ss += q[i] * q[i];
    float sc = 1.f / fmaxf(sqrtf(ss), 1e-12f);
    half8 o0, o1;
#pragma unroll
    for (int i = 0; i < 8; i++) { o0[i] = (_Float16)(q[i] * sc); o1[i] = (_Float16)(q[8 + i] * sc); }
    size_t dst = ((size_t)bh * Nc + n) * 32;
    *(half8*)&Qn[dst] = o0;
    *(half8*)&Qn[dst + 8] = o1;
    *(ushort8*)&Qn[dst + 16] = zeros;
    *(ushort8*)&Qn[dst + 24] = zeros;
  }
  {
    ushort8 u0 = *(const ushort8*)&KV[src];
    ushort8 u1 = *(const ushort8*)&KV[src + 8];
    float q[16], ss = 0.f;
#pragma unroll
    for (int i = 0; i < 8; i++) { q[i] = bf2f(u0[i]); q[8 + i] = bf2f(u1[i]); }
#pragma unroll
    for (int i = 0; i < 16; i++) ss += q[i] * q[i];
    float sc = 1.f / fmaxf(sqrtf(ss), 1e-12f);
    half8 o0, o1;
#pragma unroll
    for (int i = 0; i < 8; i++) { o0[i] = (_Float16)(q[i] * sc); o1[i] = (_Float16)(q[8 + i] * sc); }
    size_t dst = ((size_t)bh * Nc + n) * 32;
    *(half8*)&Kn[dst] = o0;
    *(half8*)&Kn[dst + 8] = o1;
    *(ushort8*)&Kn[dst + 16] = zeros;
    *(ushort8*)&Kn[dst + 24] = zeros;
  }
  {
    ushort8 u[8];
#pragma unroll
    for (int i = 0; i < 8; i++) u[i] = *(const ushort8*)&KV[src + 16 + i * 8];
    float ss = 0.f;
#pragma unroll
    for (int i = 0; i < 8; i++)
#pragma unroll
      for (int j = 0; j < 8; j++) { float x = bf2f(u[i][j]); ss += x * x; }
    float sc = 1.f / fmaxf(sqrtf(ss), 1e-12f);
#pragma unroll
    for (int i = 0; i < 8; i++)
#pragma unroll
      for (int j = 0; j < 8; j++) {
        int d = i * 8 + j;
        union { _Float16 h; unsigned short us; } cv;
        cv.h = (_Float16)(bf2f(u[i][j]) * sc);
        Vtg[((size_t)bh * DVc + d) * Nc + n] = cv.us;
      }
  }
}

// ---------------- relu^2 attention, fp16, 512-thread blocks ----------------
// R8 was latency-bound: 16 waves/CU (Occupancy 33%) couldn't hide the serial
// S->pack->PV chain + MFMA pipe latency. 512-thread blocks: 4 blocks/CU x 8
// waves = 32 waves/CU (100%), LDS 4x32KB=128<=160KB. Each wave owns 16 queries
// (1 Q-frag, acc[4] -> ~45 VGPR, fits the 64/wave needed for 8 waves/SIMD).
// K-frags loaded per 32-key group (L2-hot). Structure otherwise R8-verified.
__global__ __launch_bounds__(512, 8) void attn_kernel(const unsigned short* __restrict__ Qn,
                                                      const unsigned short* __restrict__ Kn,
                                                      const unsigned short* __restrict__ Vtg,
                                                      const unsigned short* __restrict__ QG,
                                                      unsigned short* __restrict__ outpre) {
  __shared__ unsigned short shm[2 * 64 * 128];  // vt[2][64][128] (32KB); epilogue aliases of[128][68]

  int gid = blockIdx.x;
  int xcd = gid & 7, slot = gid >> 3;
  int bh = xcd * 8 + (slot & 7);
  int q0 = (slot >> 3) * 128;
  int b = bh >> 4, h = bh & 15;
  int tid = threadIdx.x, lane = tid & 63, wave = tid >> 6;  // wave 0..7
  int ql = lane >> 4, l16 = lane & 15;
  int qw0 = q0 + wave * 16;  // this wave's 16-query base

  // Q fragment (B-operand of S-mfma), resident: q = qw0 + l16
  half8 qf = *(const half8*)&Qn[((size_t)bh * Nc + qw0 + l16) * 32 + ql * 8];

  const unsigned short* krow = Kn + ((size_t)bh * Nc) * 32;
  const unsigned short* vbase = Vtg + ((size_t)bh * DVc) * Nc;

  int lr = lane >> 4, m16 = lane & 15;

  f32x4 acc[4];
#pragma unroll
  for (int dt = 0; dt < 4; dt++) acc[dt] = (f32x4){0.f, 0.f, 0.f, 0.f};

  // prologue: stage V tile 0 into buf 0 (8 waves x 2 iters x 4 rows = 64 rows)
#pragma unroll
  for (int i = 0; i < 2; ++i) {
    int r0 = i * 32 + wave * 4;
    int d = r0 + lr;
    glds16(vbase + (size_t)d * Nc + 0 + ((m16 ^ (d & 7)) << 3), &shm[r0 * 128]);
  }

  for (int kt = 0; kt < Nc / 128; ++kt) {
    int k0 = kt * 128;
    unsigned short* vtb = &shm[(kt & 1) * 8192];
    __syncthreads();  // drains glds for this tile; all waves done reading prev buf

    // async-stage next V tile into the other buffer
    if (kt < Nc / 128 - 1) {
      unsigned short* nb = &shm[((kt + 1) & 1) * 8192];
      int kn0 = k0 + 128;
#pragma unroll
      for (int i = 0; i < 2; ++i) {
        int r0 = i * 32 + wave * 4;
        int d = r0 + lr;
        glds16(vbase + (size_t)d * Nc + kn0 + ((m16 ^ (d & 7)) << 3), &nb[r0 * 128]);
      }
    }

#pragma unroll
    for (int p = 0; p < 4; ++p) {  // 32-key group [k0+p*32, +32)
      half8 ka = *(const half8*)&krow[(size_t)(k0 + p * 32 + l16) * 32 + ql * 8];
      half8 kb = *(const half8*)&krow[(size_t)(k0 + p * 32 + 16 + l16) * 32 + ql * 8];
      f32x4 c0 = mfma16h(ka, qf, (f32x4){0.f, 0.f, 0.f, 0.f});
      f32x4 c1 = mfma16h(kb, qf, (f32x4){0.f, 0.f, 0.f, 0.f});
      // relu^2 in packed fp16: pkrtz -> pk_max -> pk_mul
      half8 pf;
      {
        union { half8 h; fp16x2 p2[4]; } w;
        fp16x2 t0 = __builtin_amdgcn_cvt_pkrtz(c0[0], c0[1]);
        fp16x2 t1 = __builtin_amdgcn_cvt_pkrtz(c0[2], c0[3]);
        fp16x2 t2 = __builtin_amdgcn_cvt_pkrtz(c1[0], c1[1]);
        fp16x2 t3 = __builtin_amdgcn_cvt_pkrtz(c1[2], c1[3]);
        const fp16x2 hz = {(__fp16)0, (__fp16)0};
        t0 = __builtin_elementwise_max(t0, hz); w.p2[0] = t0 * t0;
        t1 = __builtin_elementwise_max(t1, hz); w.p2[1] = t1 * t1;
        t2 = __builtin_elementwise_max(t2, hz); w.p2[2] = t2 * t2;
        t3 = __builtin_elementwise_max(t3, hz); w.p2[3] = t3 * t3;
        pf = w.h;
      }
      // PV: A = V^T frags from LDS (XOR-swizzled granules, permuted key order)
      int tsw = (l16 & 7) << 1;
      int s1 = ((p * 8 + ql) ^ tsw) << 2;
      int s2 = ((p * 8 + 4 + ql) ^ tsw) << 2;
#pragma unroll
      for (int dt = 0; dt < 4; ++dt) {
        const unsigned short* vrow = vtb + (dt * 16 + l16) * 128;
        union { half8 s; uint4 u; } vf;
        uint2 va = *(const uint2*)&vrow[s1];
        uint2 vb2 = *(const uint2*)&vrow[s2];
        vf.u.x = va.x; vf.u.y = va.y; vf.u.z = vb2.x; vf.u.w = vb2.y;
        acc[dt] = mfma16h(vf.s, pf, acc[dt]);
      }
    }
  }

  __syncthreads();  // all waves done with vt before 'of' aliases shm
  unsigned short(*of)[68] = (unsigned short(*)[68])shm;

  // epilogue: lane(ql,l16) holds O[q = qw0+l16][d = dt*16+ql*4+r]
  {
    float ss = 0.f;
#pragma unroll
    for (int dt = 0; dt < 4; ++dt)
#pragma unroll
      for (int r = 0; r < 4; ++r) { float v = acc[dt][r]; ss += v * v; }
    ss += __shfl_xor(ss, 16, 64);
    ss += __shfl_xor(ss, 32, 64);
    float nrm = sqrtf(ss);
    float sc = tanhf(nrm) / fmaxf(nrm, 1e-12f);
    int q = qw0 + l16;
    size_t gbase = ((size_t)(b * Nc + q)) * DIc + h * 80 + DKc;  // gate slice of QG
#pragma unroll
    for (int dt = 0; dt < 4; ++dt) {
      uint2 gu = *(const uint2*)&QG[gbase + dt * 16 + ql * 4];
      float o[4];
#pragma unroll
      for (int r = 0; r < 4; ++r) {
        unsigned short gb = (r < 2) ? (unsigned short)(gu.x >> (16 * r))
                                    : (unsigned short)(gu.y >> (16 * (r - 2)));
        float x = bf2f(gb);
        float s = x / (1.f + __expf(-x));
        float e2 = __expf(2.f * s);
        float g = 1.f - 2.f / (e2 + 1.f);  // tanh(s)
        o[r] = acc[dt][r] * sc * g;
      }
      uint2 w;
      w.x = pack2bf(o[0], o[1]);
      w.y = pack2bf(o[2], o[3]);
      *(uint2*)&of[wave * 16 + l16][dt * 16 + ql * 4] = w;
    }
  }
  __syncthreads();
  {
    int row = tid >> 2, seg = tid & 3;  // 128 rows x 4 segs of 16
    size_t obase = ((size_t)(b * Nc + q0 + row)) * (Hc * DVc) + h * DVc + seg * 16;
    *(ushort8*)&outpre[obase] = *(const ushort8*)&of[row][seg * 16];
    *(ushort8*)&outpre[obase + 8] = *(const ushort8*)&of[row][seg * 16 + 8];
  }
}

extern "C" void kernel_launch(void* const* d_in, const int* in_sizes, int n_in,
                              void* d_out, int out_size, void* d_ws, size_t ws_size,
                              hipStream_t stream) {
  const float* X = (const float*)d_in[0];     // (4,2048,1024)
  const float* Wqg = (const float*)d_in[1];   // (1024,1280)
  const float* Wkv = (const float*)d_in[2];   // (1024,1280)
  const float* Wout = (const float*)d_in[3];  // (1024,1024)
  float* out = (float*)d_out;
  (void)in_sizes; (void)n_in; (void)out_size; (void)ws_size;

  char* ws = (char*)d_ws;
  size_t off = 0;
  auto alloc = [&](size_t bytes) {
    void* p = ws + off;
    off += (bytes + 255) & ~(size_t)255;
    return p;
  };
  unsigned short* Xbf   = (unsigned short*)alloc((size_t)Mc * Dc * 2);            // 16 MB
  unsigned short* WqgT  = (unsigned short*)alloc((size_t)DIc * Dc * 2);           // 2.5 MB (WkvT MUST follow contiguously)
  unsigned short* WkvT  = (unsigned short*)alloc((size_t)DIc * Dc * 2);
  unsigned short* WoutT = (unsigned short*)alloc((size_t)Dc * Dc * 2);            // 2 MB
  unsigned short* QG    = (unsigned short*)alloc((size_t)Mc * DIc * 2);           // 20 MB
  unsigned short* KV    = (unsigned short*)alloc((size_t)Mc * DIc * 2);           // 20 MB
  unsigned short* Qn    = (unsigned short*)alloc((size_t)Bc * Hc * Nc * 32 * 2);  // 8 MB (fp16, padded)
  unsigned short* Kn    = (unsigned short*)alloc((size_t)Bc * Hc * Nc * 32 * 2);  // 8 MB
  unsigned short* Vtg   = (unsigned short*)alloc((size_t)Bc * Hc * Nc * DVc * 2); // 16 MB (fp16)
  unsigned short* outpre = Xbf;  // Xbf dead after projection GEMM; same size

  convert_x<<<(Mc * Dc / 8) / 256, 256, 0, stream>>>(X, Xbf, Mc * Dc / 8);
  transpose_convert<<<dim3(Dc / 64, DIc / 64), 256, 0, stream>>>(Wqg, WqgT, Dc, DIc);
  transpose_convert<<<dim3(Dc / 64, DIc / 64), 256, 0, stream>>>(Wkv, WkvT, Dc, DIc);
  transpose_convert<<<dim3(Dc / 64, Dc / 64), 256, 0, stream>>>(Wout, WoutT, Dc, Dc);
  gemm_proj<<<dim3(Mc / 128, 2 * DIc / 128), 256, 0, stream>>>(Xbf, WqgT, QG, KV, Dc);
  norm_kernel<<<(Mc * Hc) / 256, 256, 0, stream>>>(QG, KV, Qn, Kn, Vtg);
  attn_kernel<<<1024, 512, 0, stream>>>(Qn, Kn, Vtg, QG, outpre);
  gemm_glds<<<dim3(Mc / 128, Dc / 128), 256, 0, stream>>>(outpre, WoutT, out, Mc, Dc, Dc);
}